// Round 1
// baseline (531.030 us; speedup 1.0000x reference)
//
#include <hip/hip_runtime.h>
#include <math.h>
#include <stdint.h>

// ---------------------------------------------------------------------------
// Problem constants
//   B=8, A=1614, TOPN=6, IOU=0.25, PAD=224, OUT=224
//   conv1: 2048->128, 14x14, s1 p1   (dominant: 3.7G MAC)
//   conv2: 128->128, 14x14->7x7, s2 p1
//   conv3: 128->128, 7x7->4x4, s2 p1
//   heads: 1x1 convs -> scores (8,1614), then NMS -> top6 -> crop 224x224
// Output layout (floats): part_imgs[8*6*3*224*224]=7225344, coords[192],
//   top_prob[48], top_idx[48]  (total 7225632)
// ---------------------------------------------------------------------------

#define OFF_COORDS 7225344
#define OFF_PROB   7225536
#define OFF_IDX    7225584
#define NA 1614

// ---- weight transpose: w[128][K] -> wt[K][128] (K = Cin*9, k = ci*9+tap) ----
__global__ __launch_bounds__(256) void k_transpose_w(const float* __restrict__ w,
                                                     float* __restrict__ wt, int K)
{
    __shared__ float tile[32][33];
    int kb = blockIdx.x * 32;
    int cb = blockIdx.y * 32;
    int tx = threadIdx.x;   // 0..31
    int ty = threadIdx.y;   // 0..7
#pragma unroll
    for (int j = 0; j < 32; j += 8) {
        int co = cb + ty + j;
        int k  = kb + tx;
        tile[ty + j][tx] = (k < K) ? w[(size_t)co * K + k] : 0.0f;
    }
    __syncthreads();
#pragma unroll
    for (int j = 0; j < 32; j += 8) {
        int k  = kb + ty + j;
        int co = cb + tx;
        if (k < K) wt[(size_t)k * 128 + co] = tile[tx][ty + j];
    }
}

// ---- implicit-GEMM conv with K-split into deterministic partials ----------
// C[M x 128] = A[M x K] * Wt[K x 128], M = 8*HOUT*WOUT, K = CIN*9
// A[m][k] = in[b][ci][y*STR+dy-1][x*STR+dx-1] (zero padded), k = ci*9 + tap
// partial[blockIdx.y][m][co]
template<int CIN, int HIN, int WIN, int HOUT, int WOUT, int STR>
__global__ __launch_bounds__(256) void k_conv_gemm(const float* __restrict__ in,
                                                   const float* __restrict__ wt,
                                                   float* __restrict__ partial,
                                                   int kchunk)
{
    constexpr int PSZ  = HOUT * WOUT;
    constexpr int M    = 8 * PSZ;
    constexpr int KTOT = CIN * 9;
    __shared__ float As[16][64];
    __shared__ float Bs[16][128];
    const int t  = threadIdx.x;
    const int tx = t & 15;
    const int ty = t >> 4;
    const int mbase = blockIdx.x * 64;
    const int k0 = blockIdx.y * kchunk;
    const int k1 = (k0 + kchunk < KTOT) ? (k0 + kchunk) : KTOT;

    float acc[4][8];
#pragma unroll
    for (int r = 0; r < 4; ++r)
#pragma unroll
        for (int c = 0; c < 8; ++c) acc[r][c] = 0.0f;

    for (int ks = k0; ks < k1; ks += 16) {
        // stage A tile (16 k x 64 m), coalesced over m
#pragma unroll
        for (int i = 0; i < 4; ++i) {
            int e  = i * 256 + t;
            int kk = e >> 6;
            int mm = e & 63;
            int k  = ks + kk;
            int m  = mbase + mm;
            float v = 0.0f;
            if (k < k1 && m < M) {
                int ci  = k / 9;
                int tap = k - ci * 9;
                int b = m / PSZ;
                int p = m - b * PSZ;
                int y = p / WOUT;
                int x = p - y * WOUT;
                int yy = y * STR + tap / 3 - 1;
                int xx = x * STR + (tap % 3) - 1;
                if (yy >= 0 && yy < HIN && xx >= 0 && xx < WIN)
                    v = in[(((size_t)b * CIN + ci) * HIN + yy) * WIN + xx];
            }
            As[kk][mm] = v;
        }
        // stage B tile (16 k x 128 co), coalesced
#pragma unroll
        for (int i = 0; i < 8; ++i) {
            int e  = i * 256 + t;
            int kk = e >> 7;
            int co = e & 127;
            int k  = ks + kk;
            Bs[kk][co] = (k < k1) ? wt[(size_t)k * 128 + co] : 0.0f;
        }
        __syncthreads();
#pragma unroll
        for (int kk = 0; kk < 16; ++kk) {
            float a[4], bb[8];
            *(float4*)&a[0]  = *(const float4*)&As[kk][ty * 4];
            *(float4*)&bb[0] = *(const float4*)&Bs[kk][tx * 8];
            *(float4*)&bb[4] = *(const float4*)&Bs[kk][tx * 8 + 4];
#pragma unroll
            for (int r = 0; r < 4; ++r)
#pragma unroll
                for (int c = 0; c < 8; ++c)
                    acc[r][c] = fmaf(a[r], bb[c], acc[r][c]);
        }
        __syncthreads();
    }

    float* P = partial + (size_t)blockIdx.y * M * 128;
#pragma unroll
    for (int r = 0; r < 4; ++r) {
        int m = mbase + ty * 4 + r;
        if (m < M) {
            *(float4*)&P[(size_t)m * 128 + tx * 8]     = *(const float4*)&acc[r][0];
            *(float4*)&P[(size_t)m * 128 + tx * 8 + 4] = *(const float4*)&acc[r][4];
        }
    }
}

// ---- reduce K-split partials + bias + relu, write NCHW --------------------
template<int PSZ>
__global__ __launch_bounds__(256) void k_reduce_bias(const float* __restrict__ partial,
                                                     const float* __restrict__ bias,
                                                     float* __restrict__ out,
                                                     int ksplit, int relu)
{
    constexpr int M = 8 * PSZ;
    int idx = blockIdx.x * 256 + threadIdx.x;
    if (idx >= M * 128) return;
    int m  = idx >> 7;
    int co = idx & 127;
    float s = bias[co];
    for (int k = 0; k < ksplit; ++k) s += partial[(size_t)k * M * 128 + idx];
    if (relu) s = fmaxf(s, 0.0f);
    int b = m / PSZ;
    int p = m - b * PSZ;
    out[((size_t)b * 128 + co) * PSZ + p] = s;
}

// ---- 1x1 conv heads -> scores (8, 1614) -----------------------------------
__global__ __launch_bounds__(256) void k_heads(const float* __restrict__ d1,
                                               const float* __restrict__ d2,
                                               const float* __restrict__ d3,
                                               const float* __restrict__ w1, const float* __restrict__ b1,
                                               const float* __restrict__ w2, const float* __restrict__ b2,
                                               const float* __restrict__ w3, const float* __restrict__ b3,
                                               float* __restrict__ scores)
{
    int idx = blockIdx.x * 256 + threadIdx.x;
    if (idx >= 8 * NA) return;
    int b = idx / NA;
    int e = idx - b * NA;
    const float* d; const float* w; float bias; int psz;
    if (e < 1176) {
        int c = e / 196, p = e - c * 196;
        d = d1 + (size_t)b * 128 * 196 + p; w = w1 + c * 128; bias = b1[c]; psz = 196;
    } else if (e < 1470) {
        int e2 = e - 1176; int c = e2 / 49, p = e2 - c * 49;
        d = d2 + (size_t)b * 128 * 49 + p; w = w2 + c * 128; bias = b2[c]; psz = 49;
    } else {
        int e2 = e - 1470; int c = e2 / 16, p = e2 - c * 16;
        d = d3 + (size_t)b * 128 * 16 + p; w = w3 + c * 128; bias = b3[c]; psz = 16;
    }
    float s = bias;
    const float* dp = d;
    for (int ci = 0; ci < 128; ++ci) { s = fmaf(*dp, w[ci], s); dp += psz; }
    scores[idx] = s;
}

// ---- NMS + top-6 ----------------------------------------------------------
// Greedy NMS truncated at 6 survivors == 6 rounds of argmax + suppress.
// Tie-break: lower index (matches stable argsort / top_k).
__global__ __launch_bounds__(256) void k_nms_topk(const float* __restrict__ scores,
                                                  const float* __restrict__ anchors,
                                                  float* __restrict__ out,
                                                  int* __restrict__ boxes)
{
    __shared__ float ms[NA];
    __shared__ float ay0[NA], ax0[NA], ay1[NA], ax1[NA];
    __shared__ unsigned char picked[NA];
    __shared__ float rv[4]; __shared__ int ri[4];
    __shared__ float win[5];   // y0,x0,y1,x1,val
    int b = blockIdx.x;
    int t = threadIdx.x;
    for (int i = t; i < NA; i += 256) {
        ms[i] = scores[b * NA + i];
        float4 an = ((const float4*)anchors)[i];
        ay0[i] = an.x; ax0[i] = an.y; ay1[i] = an.z; ax1[i] = an.w;
        picked[i] = 0;
    }
    __syncthreads();
    for (int r = 0; r < 6; ++r) {
        float bv = -INFINITY; int bi = NA;
        for (int i = t; i < NA; i += 256) {
            if (!picked[i]) {
                float v = ms[i];
                if (v > bv || (v == bv && i < bi)) { bv = v; bi = i; }
            }
        }
#pragma unroll
        for (int off = 32; off > 0; off >>= 1) {
            float v2 = __shfl_down(bv, off);
            int   i2 = __shfl_down(bi, off);
            if (v2 > bv || (v2 == bv && i2 < bi)) { bv = v2; bi = i2; }
        }
        if ((t & 63) == 0) { rv[t >> 6] = bv; ri[t >> 6] = bi; }
        __syncthreads();
        if (t == 0) {
            bv = rv[0]; bi = ri[0];
            for (int wv = 1; wv < 4; ++wv)
                if (rv[wv] > bv || (rv[wv] == bv && ri[wv] < bi)) { bv = rv[wv]; bi = ri[wv]; }
            picked[bi] = 1;
            win[0] = ay0[bi]; win[1] = ax0[bi]; win[2] = ay1[bi]; win[3] = ax1[bi]; win[4] = bv;
            int o = b * 6 + r;
            out[OFF_COORDS + o * 4 + 0] = ax0[bi];
            out[OFF_COORDS + o * 4 + 1] = ay0[bi];
            out[OFF_COORDS + o * 4 + 2] = ax1[bi];
            out[OFF_COORDS + o * 4 + 3] = ay1[bi];
            out[OFF_PROB + o] = bv;
            out[OFF_IDX  + o] = (float)bi;
            boxes[o * 4 + 0] = (int)ax0[bi];
            boxes[o * 4 + 1] = (int)ay0[bi];
            boxes[o * 4 + 2] = (int)ax1[bi];
            boxes[o * 4 + 3] = (int)ay1[bi];
        }
        __syncthreads();
        float by0 = win[0], bx0 = win[1], by1 = win[2], bx1 = win[3];
        float barea = (by1 - by0) * (bx1 - bx0);
        for (int i = t; i < NA; i += 256) {
            if (picked[i]) continue;
            float ih = fmaxf(fminf(by1, ay1[i]) - fmaxf(by0, ay0[i]), 0.0f);
            float iw = fmaxf(fminf(bx1, ax1[i]) - fmaxf(bx0, ax0[i]), 0.0f);
            float inter = ih * iw;
            float area  = (ay1[i] - ay0[i]) * (ax1[i] - ax0[i]);
            float iou = inter / (barea + area - inter);
            if (iou > 0.25f) ms[i] = -INFINITY;
        }
        __syncthreads();
    }
}

// ---- bilinear crop-resize (zero-padded border handled implicitly) ---------
__global__ __launch_bounds__(256) void k_crop(const float* __restrict__ x,
                                              const int* __restrict__ boxes,
                                              float* __restrict__ out)
{
    int bid = blockIdx.x;            // ((br*3 + c)*224 + j)
    int i = threadIdx.x;
    if (i >= 224) return;
    int j   = bid % 224;
    int rem = bid / 224;
    int c   = rem % 3;
    int br  = rem / 3;
    int b   = br / 6;
    int4 bx = ((const int4*)boxes)[br];   // x0,y0,x1,y1 (padded coords)
    float tj = (float)j / 223.0f;
    float sy = (float)bx.y + tj * (float)(bx.w - 1 - bx.y);
    int y0i = (int)floorf(sy);
    int y1i = min(y0i + 1, bx.w - 1);
    float wy = sy - (float)y0i;
    float ti = (float)i / 223.0f;
    float sx = (float)bx.x + ti * (float)(bx.z - 1 - bx.x);
    int x0i = (int)floorf(sx);
    int x1i = min(x0i + 1, bx.z - 1);
    float wx = sx - (float)x0i;
    const float* img = x + ((size_t)b * 3 + c) * 448 * 448;
    auto g = [&](int yy, int xx) -> float {
        yy -= 224; xx -= 224;
        if ((unsigned)yy >= 448u || (unsigned)xx >= 448u) return 0.0f;
        return img[(size_t)yy * 448 + xx];
    };
    float g00 = g(y0i, x0i), g01 = g(y0i, x1i);
    float g10 = g(y1i, x0i), g11 = g(y1i, x1i);
    float top = (1.0f - wx) * g00 + wx * g01;
    float bot = (1.0f - wx) * g10 + wx * g11;
    out[(size_t)bid * 224 + i] = (1.0f - wy) * top + wy * bot;
}

// ---------------------------------------------------------------------------
extern "C" void kernel_launch(void* const* d_in, const int* in_sizes, int n_in,
                              void* d_out, int out_size, void* d_ws, size_t ws_size,
                              hipStream_t stream)
{
    (void)in_sizes; (void)n_in; (void)out_size;
    const float* x    = (const float*)d_in[0];
    const float* rpn  = (const float*)d_in[1];
    const float* anch = (const float*)d_in[2];
    const float* wd1  = (const float*)d_in[3];
    const float* bd1  = (const float*)d_in[4];
    const float* wd2  = (const float*)d_in[5];
    const float* bd2  = (const float*)d_in[6];
    const float* wd3  = (const float*)d_in[7];
    const float* bd3  = (const float*)d_in[8];
    const float* hw1  = (const float*)d_in[9];
    const float* hb1  = (const float*)d_in[10];
    const float* hw2  = (const float*)d_in[11];
    const float* hb2  = (const float*)d_in[12];
    const float* hw3  = (const float*)d_in[13];
    const float* hb3  = (const float*)d_in[14];
    float* out = (float*)d_out;

    char* ws = (char*)d_ws;
    size_t off = 0;
    auto alloc = [&](size_t bytes) -> void* {
        void* p = ws + off;
        off = (off + bytes + 255) & ~(size_t)255;
        return p;
    };
    float* tw1   = (float*)alloc((size_t)18432 * 128 * 4);
    float* tw2   = (float*)alloc((size_t)1152 * 128 * 4);
    float* tw3   = (float*)alloc((size_t)1152 * 128 * 4);
    float* d1    = (float*)alloc((size_t)8 * 128 * 196 * 4);
    float* d2    = (float*)alloc((size_t)8 * 128 * 49 * 4);
    float* d3    = (float*)alloc((size_t)8 * 128 * 16 * 4);
    float* sc    = (float*)alloc((size_t)8 * NA * 4);
    int*   boxes = (int*)alloc((size_t)8 * 6 * 4 * 4);
    size_t avail = (ws_size > off) ? (ws_size - off) : 0;
    float* P = (float*)(ws + off);

    auto pick_ksplit = [&](int M) -> int {
        size_t per = (size_t)M * 128 * 4;
        long long ks = (per > 0) ? (long long)(avail / per) : 1;
        if (ks > 16) ks = 16;
        if (ks < 1)  ks = 1;
        return (int)ks;
    };

    dim3 tb(32, 8);
    k_transpose_w<<<dim3(576, 4), tb, 0, stream>>>(wd1, tw1, 18432);
    k_transpose_w<<<dim3(36, 4),  tb, 0, stream>>>(wd2, tw2, 1152);
    k_transpose_w<<<dim3(36, 4),  tb, 0, stream>>>(wd3, tw3, 1152);

    // conv1: M=1568, K=18432
    int ks1 = pick_ksplit(1568);
    int kc1 = (18432 + ks1 - 1) / ks1;
    k_conv_gemm<2048, 14, 14, 14, 14, 1><<<dim3(25, ks1), 256, 0, stream>>>(rpn, tw1, P, kc1);
    k_reduce_bias<196><<<dim3((1568 * 128 + 255) / 256), 256, 0, stream>>>(P, bd1, d1, ks1, 1);

    // conv2: M=392, K=1152
    int ks2 = pick_ksplit(392);
    int kc2 = (1152 + ks2 - 1) / ks2;
    k_conv_gemm<128, 14, 14, 7, 7, 2><<<dim3(7, ks2), 256, 0, stream>>>(d1, tw2, P, kc2);
    k_reduce_bias<49><<<dim3((392 * 128 + 255) / 256), 256, 0, stream>>>(P, bd2, d2, ks2, 1);

    // conv3: M=128, K=1152
    int ks3 = pick_ksplit(128);
    int kc3 = (1152 + ks3 - 1) / ks3;
    k_conv_gemm<128, 7, 7, 4, 4, 2><<<dim3(2, ks3), 256, 0, stream>>>(d2, tw3, P, kc3);
    k_reduce_bias<16><<<dim3((128 * 128 + 255) / 256), 256, 0, stream>>>(P, bd3, d3, ks3, 1);

    k_heads<<<dim3((8 * NA + 255) / 256), 256, 0, stream>>>(d1, d2, d3, hw1, hb1, hw2, hb2, hw3, hb3, sc);
    k_nms_topk<<<dim3(8), 256, 0, stream>>>(sc, anch, out, boxes);
    k_crop<<<dim3(8 * 6 * 3 * 224), 256, 0, stream>>>(x, boxes, out);
}

// Round 2
// 291.842 us; speedup vs baseline: 1.8196x; 1.8196x over previous
//
#include <hip/hip_runtime.h>
#include <hip/hip_bf16.h>
#include <math.h>
#include <stdint.h>

// ---------------------------------------------------------------------------
// attention_net: conv stack + NMS + top6 + crop  (MI355X gfx950)
//   conv1: 2048->128, 14x14 s1 p1  -> split-bf16 MFMA GEMM (M=1568,N=128,K=18432)
//   conv2/conv3: small fp32 GEMMs (latency-bound tail, kept from R1)
// Output floats: part_imgs[7225344], coords[192], top_prob[48], top_idx[48]
// ---------------------------------------------------------------------------

#define OFF_COORDS 7225344
#define OFF_PROB   7225536
#define OFF_IDX    7225584
#define NA 1614
#define K1TOT 18432   // 9 taps * 2048 ci, k = tap*2048 + ci

typedef __attribute__((ext_vector_type(8)))  short  short8;
typedef __attribute__((ext_vector_type(16))) float  floatx16;

// ---- prep A: rpn NCHW fp32 -> padded NHWC split-bf16 ----------------------
// ah/al[b][py][px][ci], py,px in [0,16), = in[b][ci][py-1][px-1] (0 if OOB)
__global__ __launch_bounds__(256) void k_prep_a(const float* __restrict__ rpn,
                                                __hip_bfloat16* __restrict__ ah,
                                                __hip_bfloat16* __restrict__ al)
{
    __shared__ float tile[64][65];
    const int cib  = blockIdx.x * 64;
    const int posb = blockIdx.y * 64;
    const int b    = blockIdx.z;
    const int t    = threadIdx.x;
#pragma unroll
    for (int it = 0; it < 16; ++it) {
        int idx  = it * 256 + t;
        int cil  = idx >> 6;
        int posl = idx & 63;
        int pos  = posb + posl;
        int py = pos >> 4, px = pos & 15;
        int y = py - 1, x = px - 1;
        float v = 0.0f;
        if ((unsigned)y < 14u && (unsigned)x < 14u)
            v = rpn[((size_t)(b * 2048 + cib + cil) * 14 + y) * 14 + x];
        tile[cil][posl] = v;
    }
    __syncthreads();
#pragma unroll
    for (int it = 0; it < 16; ++it) {
        int idx  = it * 256 + t;
        int posl = idx >> 6;
        int cil  = idx & 63;
        float v = tile[cil][posl];
        __hip_bfloat16 h = __float2bfloat16(v);
        __hip_bfloat16 l = __float2bfloat16(v - __bfloat162float(h));
        size_t o = (size_t)(b * 256 + posb + posl) * 2048 + cib + cil;
        ah[o] = h; al[o] = l;
    }
}

// ---- prep B: wd1[co][ci][tap] -> bht[co][tap*2048+ci] split-bf16 ----------
__global__ __launch_bounds__(256) void k_prep_b(const float* __restrict__ w,
                                                __hip_bfloat16* __restrict__ bh,
                                                __hip_bfloat16* __restrict__ bl)
{
    const int tap = blockIdx.x;   // 0..8
    const int co  = blockIdx.y;   // 0..127
    const int t   = threadIdx.x;
#pragma unroll
    for (int i = 0; i < 8; ++i) {
        int ci = i * 256 + t;
        float v = w[((size_t)co * 2048 + ci) * 9 + tap];
        __hip_bfloat16 h = __float2bfloat16(v);
        __hip_bfloat16 l = __float2bfloat16(v - __bfloat162float(h));
        size_t o = (size_t)co * K1TOT + tap * 2048 + ci;
        bh[o] = h; bl[o] = l;
    }
}

// ---- conv1 as split-bf16 MFMA GEMM ----------------------------------------
// C[1568][128] = A * B, A[m][k]=nhwc[b][y+dy][x+dx][ci], B[k][n]=bht[n][k]
// Block: 128m x 128n, 4 waves (2x2 of 64m x 64n), K-stage 32, K-split grid.y
__global__ __launch_bounds__(256) void k_conv1_mfma(const short* __restrict__ ah,
                                                    const short* __restrict__ al,
                                                    const short* __restrict__ bh,
                                                    const short* __restrict__ bl,
                                                    float* __restrict__ partial,
                                                    int chunk)
{
    __shared__ short AsH[128][40];   // stage K=32, +8 pad (b128: 2-way on writes,
    __shared__ short AsL[128][40];   //  ~4-way groups on frag reads)
    __shared__ short BsH[128][40];
    __shared__ short BsL[128][40];

    const int t     = threadIdx.x;
    const int lane  = t & 63;
    const int w     = t >> 6;
    const int wm    = (w & 1) * 64;
    const int wn    = (w >> 1) * 64;
    const int lm    = lane & 31;
    const int half  = lane >> 5;
    const int mbase = blockIdx.x * 128;
    const int k0    = blockIdx.y * chunk;
    const int k1    = (k0 + chunk < K1TOT) ? (k0 + chunk) : K1TOT;

    // precompute my two A staging rows (constant across stages)
    int arow[2], apos[2]; bool aval[2];
    const int akc = (t & 3) * 8;     // k-chunk offset within stage
#pragma unroll
    for (int i = 0; i < 2; ++i) {
        int row = ((i * 256 + t) >> 2);          // 0..127
        int m   = mbase + row;
        arow[i] = row;
        aval[i] = (m < 1568);
        int mm = aval[i] ? m : 0;
        int b  = mm / 196;
        int p  = mm - b * 196;
        int y  = p / 14;
        int x  = p - y * 14;
        apos[i] = b * 256 + y * 16 + x;          // + dy*16+dx per tap
    }

    floatx16 acc[2][2];
#pragma unroll
    for (int mf = 0; mf < 2; ++mf)
#pragma unroll
        for (int nf = 0; nf < 2; ++nf)
#pragma unroll
            for (int r = 0; r < 16; ++r) acc[mf][nf][r] = 0.0f;

    const short8 zero8 = {0, 0, 0, 0, 0, 0, 0, 0};

    for (int ks = k0; ks < k1; ks += 32) {
        const int tap = ks >> 11;          // stage is 32-aligned, 2048%32==0
        const int ci0 = ks & 2047;
        const int dy  = tap / 3, dx = tap - dy * 3;
        // stage A (hi+lo)
#pragma unroll
        for (int i = 0; i < 2; ++i) {
            short8 vh = zero8, vl = zero8;
            if (aval[i]) {
                size_t g = (size_t)(apos[i] + dy * 16 + dx) * 2048 + ci0 + akc;
                vh = *(const short8*)(ah + g);
                vl = *(const short8*)(al + g);
            }
            *(short8*)&AsH[arow[i]][akc] = vh;
            *(short8*)&AsL[arow[i]][akc] = vl;
        }
        // stage B (hi+lo)
#pragma unroll
        for (int i = 0; i < 2; ++i) {
            int n = ((i * 256 + t) >> 2);
            size_t g = (size_t)n * K1TOT + ks + akc;
            *(short8*)&BsH[n][akc] = *(const short8*)(bh + g);
            *(short8*)&BsL[n][akc] = *(const short8*)(bl + g);
        }
        __syncthreads();
#pragma unroll
        for (int kst = 0; kst < 2; ++kst) {
            const int koff = kst * 16 + half * 8;
            short8 a_h[2], a_l[2], b_h[2], b_l[2];
#pragma unroll
            for (int mf = 0; mf < 2; ++mf) {
                a_h[mf] = *(const short8*)&AsH[wm + mf * 32 + lm][koff];
                a_l[mf] = *(const short8*)&AsL[wm + mf * 32 + lm][koff];
            }
#pragma unroll
            for (int nf = 0; nf < 2; ++nf) {
                b_h[nf] = *(const short8*)&BsH[wn + nf * 32 + lm][koff];
                b_l[nf] = *(const short8*)&BsL[wn + nf * 32 + lm][koff];
            }
#pragma unroll
            for (int mf = 0; mf < 2; ++mf)
#pragma unroll
                for (int nf = 0; nf < 2; ++nf) {
                    acc[mf][nf] = __builtin_amdgcn_mfma_f32_32x32x16_bf16(
                        a_h[mf], b_h[nf], acc[mf][nf], 0, 0, 0);
                    acc[mf][nf] = __builtin_amdgcn_mfma_f32_32x32x16_bf16(
                        a_h[mf], b_l[nf], acc[mf][nf], 0, 0, 0);
                    acc[mf][nf] = __builtin_amdgcn_mfma_f32_32x32x16_bf16(
                        a_l[mf], b_h[nf], acc[mf][nf], 0, 0, 0);
                }
        }
        __syncthreads();
    }

    // epilogue: D layout col=lane&31, row=(r&3)+8*(r>>2)+4*half
    float* P = partial + (size_t)blockIdx.y * 1568 * 128;
#pragma unroll
    for (int mf = 0; mf < 2; ++mf)
#pragma unroll
        for (int nf = 0; nf < 2; ++nf)
#pragma unroll
            for (int r = 0; r < 16; ++r) {
                int row = (r & 3) + 8 * (r >> 2) + 4 * half;
                int m = mbase + wm + mf * 32 + row;
                int n = wn + nf * 32 + lm;
                if (m < 1568) P[(size_t)m * 128 + n] = acc[mf][nf][r];
            }
}

// ---- weight transpose (conv2/3): w[128][K] -> wt[K][128] ------------------
__global__ __launch_bounds__(256) void k_transpose_w(const float* __restrict__ w,
                                                     float* __restrict__ wt, int K)
{
    __shared__ float tile[32][33];
    int kb = blockIdx.x * 32;
    int cb = blockIdx.y * 32;
    int tx = threadIdx.x;
    int ty = threadIdx.y;
#pragma unroll
    for (int j = 0; j < 32; j += 8) {
        int co = cb + ty + j;
        int k  = kb + tx;
        tile[ty + j][tx] = (k < K) ? w[(size_t)co * K + k] : 0.0f;
    }
    __syncthreads();
#pragma unroll
    for (int j = 0; j < 32; j += 8) {
        int k  = kb + ty + j;
        int co = cb + tx;
        if (k < K) wt[(size_t)k * 128 + co] = tile[tx][ty + j];
    }
}

// ---- fp32 implicit-GEMM conv (conv2/conv3), K-split partials --------------
template<int CIN, int HIN, int WIN, int HOUT, int WOUT, int STR>
__global__ __launch_bounds__(256) void k_conv_gemm(const float* __restrict__ in,
                                                   const float* __restrict__ wt,
                                                   float* __restrict__ partial,
                                                   int kchunk)
{
    constexpr int PSZ  = HOUT * WOUT;
    constexpr int M    = 8 * PSZ;
    constexpr int KTOT = CIN * 9;
    __shared__ float As[16][64];
    __shared__ float Bs[16][128];
    const int t  = threadIdx.x;
    const int tx = t & 15;
    const int ty = t >> 4;
    const int mbase = blockIdx.x * 64;
    const int k0 = blockIdx.y * kchunk;
    const int k1 = (k0 + kchunk < KTOT) ? (k0 + kchunk) : KTOT;

    float acc[4][8];
#pragma unroll
    for (int r = 0; r < 4; ++r)
#pragma unroll
        for (int c = 0; c < 8; ++c) acc[r][c] = 0.0f;

    for (int ks = k0; ks < k1; ks += 16) {
#pragma unroll
        for (int i = 0; i < 4; ++i) {
            int e  = i * 256 + t;
            int kk = e >> 6;
            int mm = e & 63;
            int k  = ks + kk;
            int m  = mbase + mm;
            float v = 0.0f;
            if (k < k1 && m < M) {
                int ci  = k / 9;
                int tap = k - ci * 9;
                int b = m / PSZ;
                int p = m - b * PSZ;
                int y = p / WOUT;
                int x = p - y * WOUT;
                int yy = y * STR + tap / 3 - 1;
                int xx = x * STR + (tap % 3) - 1;
                if (yy >= 0 && yy < HIN && xx >= 0 && xx < WIN)
                    v = in[(((size_t)b * CIN + ci) * HIN + yy) * WIN + xx];
            }
            As[kk][mm] = v;
        }
#pragma unroll
        for (int i = 0; i < 8; ++i) {
            int e  = i * 256 + t;
            int kk = e >> 7;
            int co = e & 127;
            int k  = ks + kk;
            Bs[kk][co] = (k < k1) ? wt[(size_t)k * 128 + co] : 0.0f;
        }
        __syncthreads();
#pragma unroll
        for (int kk = 0; kk < 16; ++kk) {
            float a[4], bb[8];
            *(float4*)&a[0]  = *(const float4*)&As[kk][ty * 4];
            *(float4*)&bb[0] = *(const float4*)&Bs[kk][tx * 8];
            *(float4*)&bb[4] = *(const float4*)&Bs[kk][tx * 8 + 4];
#pragma unroll
            for (int r = 0; r < 4; ++r)
#pragma unroll
                for (int c = 0; c < 8; ++c)
                    acc[r][c] = fmaf(a[r], bb[c], acc[r][c]);
        }
        __syncthreads();
    }

    float* P = partial + (size_t)blockIdx.y * M * 128;
#pragma unroll
    for (int r = 0; r < 4; ++r) {
        int m = mbase + ty * 4 + r;
        if (m < M) {
            *(float4*)&P[(size_t)m * 128 + tx * 8]     = *(const float4*)&acc[r][0];
            *(float4*)&P[(size_t)m * 128 + tx * 8 + 4] = *(const float4*)&acc[r][4];
        }
    }
}

// ---- reduce K-split partials + bias + relu, write NCHW --------------------
template<int PSZ>
__global__ __launch_bounds__(256) void k_reduce_bias(const float* __restrict__ partial,
                                                     const float* __restrict__ bias,
                                                     float* __restrict__ out,
                                                     int ksplit, int relu)
{
    constexpr int M = 8 * PSZ;
    int idx = blockIdx.x * 256 + threadIdx.x;
    if (idx >= M * 128) return;
    int m  = idx >> 7;
    int co = idx & 127;
    float s = bias[co];
    for (int k = 0; k < ksplit; ++k) s += partial[(size_t)k * M * 128 + idx];
    if (relu) s = fmaxf(s, 0.0f);
    int b = m / PSZ;
    int p = m - b * PSZ;
    out[((size_t)b * 128 + co) * PSZ + p] = s;
}

// ---- 1x1 conv heads -> scores (8, 1614) -----------------------------------
__global__ __launch_bounds__(256) void k_heads(const float* __restrict__ d1,
                                               const float* __restrict__ d2,
                                               const float* __restrict__ d3,
                                               const float* __restrict__ w1, const float* __restrict__ b1,
                                               const float* __restrict__ w2, const float* __restrict__ b2,
                                               const float* __restrict__ w3, const float* __restrict__ b3,
                                               float* __restrict__ scores)
{
    int idx = blockIdx.x * 256 + threadIdx.x;
    if (idx >= 8 * NA) return;
    int b = idx / NA;
    int e = idx - b * NA;
    const float* d; const float* w; float bias; int psz;
    if (e < 1176) {
        int c = e / 196, p = e - c * 196;
        d = d1 + (size_t)b * 128 * 196 + p; w = w1 + c * 128; bias = b1[c]; psz = 196;
    } else if (e < 1470) {
        int e2 = e - 1176; int c = e2 / 49, p = e2 - c * 49;
        d = d2 + (size_t)b * 128 * 49 + p; w = w2 + c * 128; bias = b2[c]; psz = 49;
    } else {
        int e2 = e - 1470; int c = e2 / 16, p = e2 - c * 16;
        d = d3 + (size_t)b * 128 * 16 + p; w = w3 + c * 128; bias = b3[c]; psz = 16;
    }
    float s = bias;
    const float* dp = d;
    for (int ci = 0; ci < 128; ++ci) { s = fmaf(*dp, w[ci], s); dp += psz; }
    scores[idx] = s;
}

// ---- NMS + top-6 (greedy NMS truncated at 6 == 6x argmax+suppress) --------
__global__ __launch_bounds__(256) void k_nms_topk(const float* __restrict__ scores,
                                                  const float* __restrict__ anchors,
                                                  float* __restrict__ out,
                                                  int* __restrict__ boxes)
{
    __shared__ float ms[NA];
    __shared__ float ay0[NA], ax0[NA], ay1[NA], ax1[NA];
    __shared__ unsigned char picked[NA];
    __shared__ float rv[4]; __shared__ int ri[4];
    __shared__ float win[5];
    int b = blockIdx.x;
    int t = threadIdx.x;
    for (int i = t; i < NA; i += 256) {
        ms[i] = scores[b * NA + i];
        float4 an = ((const float4*)anchors)[i];
        ay0[i] = an.x; ax0[i] = an.y; ay1[i] = an.z; ax1[i] = an.w;
        picked[i] = 0;
    }
    __syncthreads();
    for (int r = 0; r < 6; ++r) {
        float bv = -INFINITY; int bi = NA;
        for (int i = t; i < NA; i += 256) {
            if (!picked[i]) {
                float v = ms[i];
                if (v > bv || (v == bv && i < bi)) { bv = v; bi = i; }
            }
        }
#pragma unroll
        for (int off = 32; off > 0; off >>= 1) {
            float v2 = __shfl_down(bv, off);
            int   i2 = __shfl_down(bi, off);
            if (v2 > bv || (v2 == bv && i2 < bi)) { bv = v2; bi = i2; }
        }
        if ((t & 63) == 0) { rv[t >> 6] = bv; ri[t >> 6] = bi; }
        __syncthreads();
        if (t == 0) {
            bv = rv[0]; bi = ri[0];
            for (int wv = 1; wv < 4; ++wv)
                if (rv[wv] > bv || (rv[wv] == bv && ri[wv] < bi)) { bv = rv[wv]; bi = ri[wv]; }
            picked[bi] = 1;
            win[0] = ay0[bi]; win[1] = ax0[bi]; win[2] = ay1[bi]; win[3] = ax1[bi]; win[4] = bv;
            int o = b * 6 + r;
            out[OFF_COORDS + o * 4 + 0] = ax0[bi];
            out[OFF_COORDS + o * 4 + 1] = ay0[bi];
            out[OFF_COORDS + o * 4 + 2] = ax1[bi];
            out[OFF_COORDS + o * 4 + 3] = ay1[bi];
            out[OFF_PROB + o] = bv;
            out[OFF_IDX  + o] = (float)bi;
            boxes[o * 4 + 0] = (int)ax0[bi];
            boxes[o * 4 + 1] = (int)ay0[bi];
            boxes[o * 4 + 2] = (int)ax1[bi];
            boxes[o * 4 + 3] = (int)ay1[bi];
        }
        __syncthreads();
        float by0 = win[0], bx0 = win[1], by1 = win[2], bx1 = win[3];
        float barea = (by1 - by0) * (bx1 - bx0);
        for (int i = t; i < NA; i += 256) {
            if (picked[i]) continue;
            float ih = fmaxf(fminf(by1, ay1[i]) - fmaxf(by0, ay0[i]), 0.0f);
            float iw = fmaxf(fminf(bx1, ax1[i]) - fmaxf(bx0, ax0[i]), 0.0f);
            float inter = ih * iw;
            float area  = (ay1[i] - ay0[i]) * (ax1[i] - ax0[i]);
            float iou = inter / (barea + area - inter);
            if (iou > 0.25f) ms[i] = -INFINITY;
        }
        __syncthreads();
    }
}

// ---- bilinear crop-resize --------------------------------------------------
__global__ __launch_bounds__(256) void k_crop(const float* __restrict__ x,
                                              const int* __restrict__ boxes,
                                              float* __restrict__ out)
{
    int bid = blockIdx.x;
    int i = threadIdx.x;
    if (i >= 224) return;
    int j   = bid % 224;
    int rem = bid / 224;
    int c   = rem % 3;
    int br  = rem / 3;
    int b   = br / 6;
    int4 bx = ((const int4*)boxes)[br];
    float tj = (float)j / 223.0f;
    float sy = (float)bx.y + tj * (float)(bx.w - 1 - bx.y);
    int y0i = (int)floorf(sy);
    int y1i = min(y0i + 1, bx.w - 1);
    float wy = sy - (float)y0i;
    float ti = (float)i / 223.0f;
    float sx = (float)bx.x + ti * (float)(bx.z - 1 - bx.x);
    int x0i = (int)floorf(sx);
    int x1i = min(x0i + 1, bx.z - 1);
    float wx = sx - (float)x0i;
    const float* img = x + ((size_t)b * 3 + c) * 448 * 448;
    auto g = [&](int yy, int xx) -> float {
        yy -= 224; xx -= 224;
        if ((unsigned)yy >= 448u || (unsigned)xx >= 448u) return 0.0f;
        return img[(size_t)yy * 448 + xx];
    };
    float g00 = g(y0i, x0i), g01 = g(y0i, x1i);
    float g10 = g(y1i, x0i), g11 = g(y1i, x1i);
    float top = (1.0f - wx) * g00 + wx * g01;
    float bot = (1.0f - wx) * g10 + wx * g11;
    out[(size_t)bid * 224 + i] = (1.0f - wy) * top + wy * bot;
}

// ---------------------------------------------------------------------------
extern "C" void kernel_launch(void* const* d_in, const int* in_sizes, int n_in,
                              void* d_out, int out_size, void* d_ws, size_t ws_size,
                              hipStream_t stream)
{
    (void)in_sizes; (void)n_in; (void)out_size;
    const float* x    = (const float*)d_in[0];
    const float* rpn  = (const float*)d_in[1];
    const float* anch = (const float*)d_in[2];
    const float* wd1  = (const float*)d_in[3];
    const float* bd1  = (const float*)d_in[4];
    const float* wd2  = (const float*)d_in[5];
    const float* bd2  = (const float*)d_in[6];
    const float* wd3  = (const float*)d_in[7];
    const float* bd3  = (const float*)d_in[8];
    const float* hw1  = (const float*)d_in[9];
    const float* hb1  = (const float*)d_in[10];
    const float* hw2  = (const float*)d_in[11];
    const float* hb2  = (const float*)d_in[12];
    const float* hw3  = (const float*)d_in[13];
    const float* hb3  = (const float*)d_in[14];
    float* out = (float*)d_out;

    char* ws = (char*)d_ws;
    size_t off = 0;
    auto alloc = [&](size_t bytes) -> void* {
        void* p = ws + off;
        off = (off + bytes + 255) & ~(size_t)255;
        return p;
    };
    __hip_bfloat16* ahb = (__hip_bfloat16*)alloc((size_t)8 * 256 * 2048 * 2);
    __hip_bfloat16* alb = (__hip_bfloat16*)alloc((size_t)8 * 256 * 2048 * 2);
    __hip_bfloat16* bhb = (__hip_bfloat16*)alloc((size_t)128 * K1TOT * 2);
    __hip_bfloat16* blb = (__hip_bfloat16*)alloc((size_t)128 * K1TOT * 2);
    float* tw2   = (float*)alloc((size_t)1152 * 128 * 4);
    float* tw3   = (float*)alloc((size_t)1152 * 128 * 4);
    float* d1    = (float*)alloc((size_t)8 * 128 * 196 * 4);
    float* d2    = (float*)alloc((size_t)8 * 128 * 49 * 4);
    float* d3    = (float*)alloc((size_t)8 * 128 * 16 * 4);
    float* sc    = (float*)alloc((size_t)8 * NA * 4);
    int*   boxes = (int*)alloc((size_t)8 * 6 * 4 * 4);
    size_t avail = (ws_size > off) ? (ws_size - off) : 0;
    float* P = (float*)(ws + off);

    // K-split for conv1 MFMA partials
    long long s1 = (long long)(avail / ((size_t)1568 * 128 * 4));
    if (s1 > 48) s1 = 48;
    if (s1 < 1)  s1 = 1;
    int S1 = (int)s1;
    int chunk1 = ((K1TOT + S1 * 32 - 1) / (S1 * 32)) * 32;

    auto pick_ksplit = [&](int M) -> int {
        size_t per = (size_t)M * 128 * 4;
        long long ks = (per > 0) ? (long long)(avail / per) : 1;
        if (ks > 16) ks = 16;
        if (ks < 1)  ks = 1;
        return (int)ks;
    };

    // --- conv1: split-bf16 MFMA path ---
    k_prep_a<<<dim3(32, 4, 8), 256, 0, stream>>>(rpn, ahb, alb);
    k_prep_b<<<dim3(9, 128), 256, 0, stream>>>(wd1, bhb, blb);
    k_conv1_mfma<<<dim3(13, S1), 256, 0, stream>>>((const short*)ahb, (const short*)alb,
                                                   (const short*)bhb, (const short*)blb,
                                                   P, chunk1);
    k_reduce_bias<196><<<dim3((1568 * 128 + 255) / 256), 256, 0, stream>>>(P, bd1, d1, S1, 1);

    // --- conv2/conv3: fp32 path ---
    dim3 tb(32, 8);
    k_transpose_w<<<dim3(36, 4), tb, 0, stream>>>(wd2, tw2, 1152);
    k_transpose_w<<<dim3(36, 4), tb, 0, stream>>>(wd3, tw3, 1152);

    int ks2 = pick_ksplit(392);
    int kc2 = (1152 + ks2 - 1) / ks2;
    k_conv_gemm<128, 14, 14, 7, 7, 2><<<dim3(7, ks2), 256, 0, stream>>>(d1, tw2, P, kc2);
    k_reduce_bias<49><<<dim3((392 * 128 + 255) / 256), 256, 0, stream>>>(P, bd2, d2, ks2, 1);

    int ks3 = pick_ksplit(128);
    int kc3 = (1152 + ks3 - 1) / ks3;
    k_conv_gemm<128, 7, 7, 4, 4, 2><<<dim3(2, ks3), 256, 0, stream>>>(d2, tw3, P, kc3);
    k_reduce_bias<16><<<dim3((128 * 128 + 255) / 256), 256, 0, stream>>>(P, bd3, d3, ks3, 1);

    k_heads<<<dim3((8 * NA + 255) / 256), 256, 0, stream>>>(d1, d2, d3, hw1, hb1, hw2, hb2, hw3, hb3, sc);
    k_nms_topk<<<dim3(8), 256, 0, stream>>>(sc, anch, out, boxes);
    k_crop<<<dim3(8 * 6 * 3 * 224), 256, 0, stream>>>(x, boxes, out);
}

// Round 3
// 259.128 us; speedup vs baseline: 2.0493x; 1.1262x over previous
//
#include <hip/hip_runtime.h>
#include <hip/hip_bf16.h>
#include <math.h>
#include <stdint.h>

// ---------------------------------------------------------------------------
// attention_net (MI355X gfx950)
//   conv1: 2048->128 14x14 s1p1 | conv2: 128->128 ->7x7 s2p1 | conv3: ->4x4
//   All three convs: split-bf16 (hi+lo) MFMA 32x32x16, NHWC padded-16x16 A.
//   Then 1x1 heads -> scores(8,1614) -> greedy-NMS top6 -> bilinear crop.
// Output floats: part_imgs[7225344], coords[192], top_prob[48], top_idx[48]
// ---------------------------------------------------------------------------

#define OFF_COORDS 7225344
#define OFF_PROB   7225536
#define OFF_IDX    7225584
#define NA 1614
#define K1TOT 18432

typedef __attribute__((ext_vector_type(8)))  short  short8;
typedef __attribute__((ext_vector_type(16))) float  floatx16;

// ---- prep A: rpn NCHW fp32 -> padded(16x16) NHWC split-bf16 ---------------
__global__ __launch_bounds__(256) void k_prep_a(const float* __restrict__ rpn,
                                                __hip_bfloat16* __restrict__ ah,
                                                __hip_bfloat16* __restrict__ al)
{
    __shared__ float tile[64][65];
    const int cib  = blockIdx.x * 64;
    const int posb = blockIdx.y * 64;
    const int b    = blockIdx.z;
    const int t    = threadIdx.x;
#pragma unroll
    for (int it = 0; it < 16; ++it) {
        int idx  = it * 256 + t;
        int cil  = idx >> 6;
        int posl = idx & 63;
        int pos  = posb + posl;
        int py = pos >> 4, px = pos & 15;
        int y = py - 1, x = px - 1;
        float v = 0.0f;
        if ((unsigned)y < 14u && (unsigned)x < 14u)
            v = rpn[((size_t)(b * 2048 + cib + cil) * 14 + y) * 14 + x];
        tile[cil][posl] = v;
    }
    __syncthreads();
#pragma unroll
    for (int it = 0; it < 16; ++it) {
        int idx  = it * 256 + t;
        int posl = idx >> 6;
        int cil  = idx & 63;
        float v = tile[cil][posl];
        __hip_bfloat16 h = __float2bfloat16(v);
        __hip_bfloat16 l = __float2bfloat16(v - __bfloat162float(h));
        size_t o = (size_t)(b * 256 + posb + posl) * 2048 + cib + cil;
        ah[o] = h; al[o] = l;
    }
}

// ---- prep B (conv1): wd1[co][ci][tap] -> b[co][tap*2048+ci] split-bf16 ----
__global__ __launch_bounds__(256) void k_prep_b(const float* __restrict__ w,
                                                __hip_bfloat16* __restrict__ bh,
                                                __hip_bfloat16* __restrict__ bl)
{
    const int tap = blockIdx.x;
    const int co  = blockIdx.y;
    const int t   = threadIdx.x;
#pragma unroll
    for (int i = 0; i < 8; ++i) {
        int ci = i * 256 + t;
        float v = w[((size_t)co * 2048 + ci) * 9 + tap];
        __hip_bfloat16 h = __float2bfloat16(v);
        __hip_bfloat16 l = __float2bfloat16(v - __bfloat162float(h));
        size_t o = (size_t)co * K1TOT + tap * 2048 + ci;
        bh[o] = h; bl[o] = l;
    }
}

// ---- prep B (conv2/conv3): w[co][ci][tap] (128x128x9) -> b[co][tap*128+ci]
__global__ __launch_bounds__(128) void k_prep_w23(const float* __restrict__ w2,
                                                  const float* __restrict__ w3,
                                                  __hip_bfloat16* __restrict__ b2h,
                                                  __hip_bfloat16* __restrict__ b2l,
                                                  __hip_bfloat16* __restrict__ b3h,
                                                  __hip_bfloat16* __restrict__ b3l)
{
    const int tap = blockIdx.x;
    const int co  = blockIdx.y;
    const int z   = blockIdx.z;
    const int ci  = threadIdx.x;
    const float* w = z ? w3 : w2;
    __hip_bfloat16* bh = z ? b3h : b2h;
    __hip_bfloat16* bl = z ? b3l : b2l;
    float v = w[((size_t)co * 128 + ci) * 9 + tap];
    __hip_bfloat16 h = __float2bfloat16(v);
    __hip_bfloat16 l = __float2bfloat16(v - __bfloat162float(h));
    size_t o = (size_t)co * 1152 + tap * 128 + ci;
    bh[o] = h; bl[o] = l;
}

// ---- unified split-bf16 MFMA implicit-GEMM conv ---------------------------
// C[MTOT][128] = A*B ; A[m][k], k=tap*CIN+ci, A from padded NHWC [b][16][16][CIN]
// m -> b=m/POSN, p=m%POSN, y=p/OW, x=p%OW ; pos = b*256 + (y*STR+dy)*16 + x*STR+dx
// Block 128m x 128n, 4 waves (2x2 of 64x64), K-stage 32, K-split grid.y
template<int POSN, int OW, int STR, int CIN, int MTOT>
__global__ __launch_bounds__(256) void k_conv_mfma(const short* __restrict__ ah,
                                                   const short* __restrict__ al,
                                                   const short* __restrict__ bh,
                                                   const short* __restrict__ bl,
                                                   float* __restrict__ partial,
                                                   int chunk)
{
    constexpr int KTOT = CIN * 9;
    __shared__ short AsH[128][40];
    __shared__ short AsL[128][40];
    __shared__ short BsH[128][40];
    __shared__ short BsL[128][40];

    const int t     = threadIdx.x;
    const int lane  = t & 63;
    const int w     = t >> 6;
    const int wm    = (w & 1) * 64;
    const int wn    = (w >> 1) * 64;
    const int lm    = lane & 31;
    const int half  = lane >> 5;
    const int mbase = blockIdx.x * 128;
    const int k0    = blockIdx.y * chunk;
    const int k1    = (k0 + chunk < KTOT) ? (k0 + chunk) : KTOT;

    int arow[2], apos[2]; bool aval[2];
    const int akc = (t & 3) * 8;
#pragma unroll
    for (int i = 0; i < 2; ++i) {
        int row = ((i * 256 + t) >> 2);
        int m   = mbase + row;
        arow[i] = row;
        aval[i] = (m < MTOT);
        int mm = aval[i] ? m : 0;
        int b  = mm / POSN;
        int p  = mm - b * POSN;
        int y  = p / OW;
        int x  = p - y * OW;
        apos[i] = b * 256 + y * STR * 16 + x * STR;
    }

    floatx16 acc[2][2];
#pragma unroll
    for (int mf = 0; mf < 2; ++mf)
#pragma unroll
        for (int nf = 0; nf < 2; ++nf)
#pragma unroll
            for (int r = 0; r < 16; ++r) acc[mf][nf][r] = 0.0f;

    const short8 zero8 = {0, 0, 0, 0, 0, 0, 0, 0};

    for (int ks = k0; ks < k1; ks += 32) {
        const int tap = ks / CIN;        // stage (32) never straddles a tap
        const int ci0 = ks - tap * CIN;
        const int dy  = tap / 3, dx = tap - dy * 3;
#pragma unroll
        for (int i = 0; i < 2; ++i) {
            short8 vh = zero8, vl = zero8;
            if (aval[i]) {
                size_t g = (size_t)(apos[i] + dy * 16 + dx) * CIN + ci0 + akc;
                vh = *(const short8*)(ah + g);
                vl = *(const short8*)(al + g);
            }
            *(short8*)&AsH[arow[i]][akc] = vh;
            *(short8*)&AsL[arow[i]][akc] = vl;
        }
#pragma unroll
        for (int i = 0; i < 2; ++i) {
            int n = ((i * 256 + t) >> 2);
            size_t g = (size_t)n * KTOT + ks + akc;
            *(short8*)&BsH[n][akc] = *(const short8*)(bh + g);
            *(short8*)&BsL[n][akc] = *(const short8*)(bl + g);
        }
        __syncthreads();
#pragma unroll
        for (int kst = 0; kst < 2; ++kst) {
            const int koff = kst * 16 + half * 8;
            short8 a_h[2], a_l[2], b_h[2], b_l[2];
#pragma unroll
            for (int mf = 0; mf < 2; ++mf) {
                a_h[mf] = *(const short8*)&AsH[wm + mf * 32 + lm][koff];
                a_l[mf] = *(const short8*)&AsL[wm + mf * 32 + lm][koff];
            }
#pragma unroll
            for (int nf = 0; nf < 2; ++nf) {
                b_h[nf] = *(const short8*)&BsH[wn + nf * 32 + lm][koff];
                b_l[nf] = *(const short8*)&BsL[wn + nf * 32 + lm][koff];
            }
#pragma unroll
            for (int mf = 0; mf < 2; ++mf)
#pragma unroll
                for (int nf = 0; nf < 2; ++nf) {
                    acc[mf][nf] = __builtin_amdgcn_mfma_f32_32x32x16_bf16(
                        a_h[mf], b_h[nf], acc[mf][nf], 0, 0, 0);
                    acc[mf][nf] = __builtin_amdgcn_mfma_f32_32x32x16_bf16(
                        a_h[mf], b_l[nf], acc[mf][nf], 0, 0, 0);
                    acc[mf][nf] = __builtin_amdgcn_mfma_f32_32x32x16_bf16(
                        a_l[mf], b_h[nf], acc[mf][nf], 0, 0, 0);
                }
        }
        __syncthreads();
    }

    float* P = partial + (size_t)blockIdx.y * MTOT * 128;
#pragma unroll
    for (int mf = 0; mf < 2; ++mf)
#pragma unroll
        for (int nf = 0; nf < 2; ++nf)
#pragma unroll
            for (int r = 0; r < 16; ++r) {
                int row = (r & 3) + 8 * (r >> 2) + 4 * half;
                int m = mbase + wm + mf * 32 + row;
                int n = wn + nf * 32 + lm;
                if (m < MTOT) P[(size_t)m * 128 + n] = acc[mf][nf][r];
            }
}

// ---- fused reduce: partials + bias + relu -> NHWC fp32 + padded bf16 hi/lo
// grid covers padded slots [8][256][128]; OWV = valid spatial size (14 or 7)
template<int POSN, int OWV>
__global__ __launch_bounds__(256) void k_reduce_pad(const float* __restrict__ partial,
                                                    const float* __restrict__ bias,
                                                    float* __restrict__ dn,
                                                    __hip_bfloat16* __restrict__ ph,
                                                    __hip_bfloat16* __restrict__ pl,
                                                    int S)
{
    constexpr int MTOT = 8 * POSN;
    int idx = blockIdx.x * 256 + threadIdx.x;   // < 8*256*128
    int b   = idx >> 15;
    int pos = (idx >> 7) & 255;
    int co  = idx & 127;
    int y = (pos >> 4) - 1;
    int x = (pos & 15) - 1;
    if ((unsigned)y < (unsigned)OWV && (unsigned)x < (unsigned)OWV) {
        int m = b * POSN + y * OWV + x;
        float s = bias[co];
        for (int k = 0; k < S; ++k) s += partial[(size_t)k * MTOT * 128 + m * 128 + co];
        s = fmaxf(s, 0.0f);
        dn[(size_t)m * 128 + co] = s;
        __hip_bfloat16 h = __float2bfloat16(s);
        __hip_bfloat16 l = __float2bfloat16(s - __bfloat162float(h));
        ph[idx] = h; pl[idx] = l;
    } else {
        ph[idx] = __float2bfloat16(0.0f);
        pl[idx] = __float2bfloat16(0.0f);
    }
}

// ---- reduce conv3 (no pad output) -> NHWC fp32 [8][16][128] ---------------
__global__ __launch_bounds__(256) void k_reduce3(const float* __restrict__ partial,
                                                 const float* __restrict__ bias,
                                                 float* __restrict__ dn, int S)
{
    int idx = blockIdx.x * 256 + threadIdx.x;   // < 8*16*128
    int co  = idx & 127;
    float s = bias[co];
    for (int k = 0; k < S; ++k) s += partial[(size_t)k * 128 * 128 + idx];
    dn[idx] = fmaxf(s, 0.0f);
}

// ---- 1x1 heads on NHWC fp32: contiguous 128-deep dots ---------------------
__global__ __launch_bounds__(256) void k_heads(const float* __restrict__ d1n,
                                               const float* __restrict__ d2n,
                                               const float* __restrict__ d3n,
                                               const float* __restrict__ w1, const float* __restrict__ b1,
                                               const float* __restrict__ w2, const float* __restrict__ b2,
                                               const float* __restrict__ w3, const float* __restrict__ b3,
                                               float* __restrict__ scores)
{
    int idx = blockIdx.x * 256 + threadIdx.x;
    if (idx >= 8 * NA) return;
    int b = idx / NA;
    int e = idx - b * NA;
    const float* d; const float* w; float bias;
    if (e < 1176) {
        int c = e / 196, p = e - c * 196;
        d = d1n + (size_t)(b * 196 + p) * 128; w = w1 + c * 128; bias = b1[c];
    } else if (e < 1470) {
        int e2 = e - 1176; int c = e2 / 49, p = e2 - c * 49;
        d = d2n + (size_t)(b * 49 + p) * 128; w = w2 + c * 128; bias = b2[c];
    } else {
        int e2 = e - 1470; int c = e2 / 16, p = e2 - c * 16;
        d = d3n + (size_t)(b * 16 + p) * 128; w = w3 + c * 128; bias = b3[c];
    }
    float s = bias;
#pragma unroll
    for (int i = 0; i < 32; ++i) {
        float4 dv = ((const float4*)d)[i];
        float4 wv = ((const float4*)w)[i];
        s = fmaf(dv.x, wv.x, s);
        s = fmaf(dv.y, wv.y, s);
        s = fmaf(dv.z, wv.z, s);
        s = fmaf(dv.w, wv.w, s);
    }
    scores[idx] = s;
}

// ---- NMS + top-6 (greedy NMS truncated at 6 == 6x argmax+suppress) --------
__global__ __launch_bounds__(256) void k_nms_topk(const float* __restrict__ scores,
                                                  const float* __restrict__ anchors,
                                                  float* __restrict__ out,
                                                  int* __restrict__ boxes)
{
    __shared__ float ms[NA];
    __shared__ float ay0[NA], ax0[NA], ay1[NA], ax1[NA];
    __shared__ unsigned char picked[NA];
    __shared__ float rv[4]; __shared__ int ri[4];
    __shared__ float win[5];
    int b = blockIdx.x;
    int t = threadIdx.x;
    for (int i = t; i < NA; i += 256) {
        ms[i] = scores[b * NA + i];
        float4 an = ((const float4*)anchors)[i];
        ay0[i] = an.x; ax0[i] = an.y; ay1[i] = an.z; ax1[i] = an.w;
        picked[i] = 0;
    }
    __syncthreads();
    for (int r = 0; r < 6; ++r) {
        float bv = -INFINITY; int bi = NA;
        for (int i = t; i < NA; i += 256) {
            if (!picked[i]) {
                float v = ms[i];
                if (v > bv || (v == bv && i < bi)) { bv = v; bi = i; }
            }
        }
#pragma unroll
        for (int off = 32; off > 0; off >>= 1) {
            float v2 = __shfl_down(bv, off);
            int   i2 = __shfl_down(bi, off);
            if (v2 > bv || (v2 == bv && i2 < bi)) { bv = v2; bi = i2; }
        }
        if ((t & 63) == 0) { rv[t >> 6] = bv; ri[t >> 6] = bi; }
        __syncthreads();
        if (t == 0) {
            bv = rv[0]; bi = ri[0];
            for (int wv = 1; wv < 4; ++wv)
                if (rv[wv] > bv || (rv[wv] == bv && ri[wv] < bi)) { bv = rv[wv]; bi = ri[wv]; }
            picked[bi] = 1;
            win[0] = ay0[bi]; win[1] = ax0[bi]; win[2] = ay1[bi]; win[3] = ax1[bi]; win[4] = bv;
            int o = b * 6 + r;
            out[OFF_COORDS + o * 4 + 0] = ax0[bi];
            out[OFF_COORDS + o * 4 + 1] = ay0[bi];
            out[OFF_COORDS + o * 4 + 2] = ax1[bi];
            out[OFF_COORDS + o * 4 + 3] = ay1[bi];
            out[OFF_PROB + o] = bv;
            out[OFF_IDX  + o] = (float)bi;
            boxes[o * 4 + 0] = (int)ax0[bi];
            boxes[o * 4 + 1] = (int)ay0[bi];
            boxes[o * 4 + 2] = (int)ax1[bi];
            boxes[o * 4 + 3] = (int)ay1[bi];
        }
        __syncthreads();
        float by0 = win[0], bx0 = win[1], by1 = win[2], bx1 = win[3];
        float barea = (by1 - by0) * (bx1 - bx0);
        for (int i = t; i < NA; i += 256) {
            if (picked[i]) continue;
            float ih = fmaxf(fminf(by1, ay1[i]) - fmaxf(by0, ay0[i]), 0.0f);
            float iw = fmaxf(fminf(bx1, ax1[i]) - fmaxf(bx0, ax0[i]), 0.0f);
            float inter = ih * iw;
            float area  = (ay1[i] - ay0[i]) * (ax1[i] - ax0[i]);
            float iou = inter / (barea + area - inter);
            if (iou > 0.25f) ms[i] = -INFINITY;
        }
        __syncthreads();
    }
}

// ---- bilinear crop-resize --------------------------------------------------
__global__ __launch_bounds__(256) void k_crop(const float* __restrict__ x,
                                              const int* __restrict__ boxes,
                                              float* __restrict__ out)
{
    int bid = blockIdx.x;
    int i = threadIdx.x;
    if (i >= 224) return;
    int j   = bid % 224;
    int rem = bid / 224;
    int c   = rem % 3;
    int br  = rem / 3;
    int b   = br / 6;
    int4 bx = ((const int4*)boxes)[br];
    float tj = (float)j / 223.0f;
    float sy = (float)bx.y + tj * (float)(bx.w - 1 - bx.y);
    int y0i = (int)floorf(sy);
    int y1i = min(y0i + 1, bx.w - 1);
    float wy = sy - (float)y0i;
    float ti = (float)i / 223.0f;
    float sx = (float)bx.x + ti * (float)(bx.z - 1 - bx.x);
    int x0i = (int)floorf(sx);
    int x1i = min(x0i + 1, bx.z - 1);
    float wx = sx - (float)x0i;
    const float* img = x + ((size_t)b * 3 + c) * 448 * 448;
    auto g = [&](int yy, int xx) -> float {
        yy -= 224; xx -= 224;
        if ((unsigned)yy >= 448u || (unsigned)xx >= 448u) return 0.0f;
        return img[(size_t)yy * 448 + xx];
    };
    float g00 = g(y0i, x0i), g01 = g(y0i, x1i);
    float g10 = g(y1i, x0i), g11 = g(y1i, x1i);
    float top = (1.0f - wx) * g00 + wx * g01;
    float bot = (1.0f - wx) * g10 + wx * g11;
    out[(size_t)bid * 224 + i] = (1.0f - wy) * top + wy * bot;
}

// ---------------------------------------------------------------------------
extern "C" void kernel_launch(void* const* d_in, const int* in_sizes, int n_in,
                              void* d_out, int out_size, void* d_ws, size_t ws_size,
                              hipStream_t stream)
{
    (void)in_sizes; (void)n_in; (void)out_size;
    const float* x    = (const float*)d_in[0];
    const float* rpn  = (const float*)d_in[1];
    const float* anch = (const float*)d_in[2];
    const float* wd1  = (const float*)d_in[3];
    const float* bd1  = (const float*)d_in[4];
    const float* wd2  = (const float*)d_in[5];
    const float* bd2  = (const float*)d_in[6];
    const float* wd3  = (const float*)d_in[7];
    const float* bd3  = (const float*)d_in[8];
    const float* hw1  = (const float*)d_in[9];
    const float* hb1  = (const float*)d_in[10];
    const float* hw2  = (const float*)d_in[11];
    const float* hb2  = (const float*)d_in[12];
    const float* hw3  = (const float*)d_in[13];
    const float* hb3  = (const float*)d_in[14];
    float* out = (float*)d_out;

    char* ws = (char*)d_ws;
    size_t off = 0;
    auto alloc = [&](size_t bytes) -> void* {
        void* p = ws + off;
        off = (off + bytes + 255) & ~(size_t)255;
        return p;
    };
    __hip_bfloat16* ahb  = (__hip_bfloat16*)alloc((size_t)8 * 256 * 2048 * 2);
    __hip_bfloat16* alb  = (__hip_bfloat16*)alloc((size_t)8 * 256 * 2048 * 2);
    __hip_bfloat16* b1h  = (__hip_bfloat16*)alloc((size_t)128 * K1TOT * 2);
    __hip_bfloat16* b1l  = (__hip_bfloat16*)alloc((size_t)128 * K1TOT * 2);
    __hip_bfloat16* b2h  = (__hip_bfloat16*)alloc((size_t)128 * 1152 * 2);
    __hip_bfloat16* b2l  = (__hip_bfloat16*)alloc((size_t)128 * 1152 * 2);
    __hip_bfloat16* b3h  = (__hip_bfloat16*)alloc((size_t)128 * 1152 * 2);
    __hip_bfloat16* b3l  = (__hip_bfloat16*)alloc((size_t)128 * 1152 * 2);
    __hip_bfloat16* d1ph = (__hip_bfloat16*)alloc((size_t)8 * 256 * 128 * 2);
    __hip_bfloat16* d1pl = (__hip_bfloat16*)alloc((size_t)8 * 256 * 128 * 2);
    __hip_bfloat16* d2ph = (__hip_bfloat16*)alloc((size_t)8 * 256 * 128 * 2);
    __hip_bfloat16* d2pl = (__hip_bfloat16*)alloc((size_t)8 * 256 * 128 * 2);
    float* d1n  = (float*)alloc((size_t)8 * 196 * 128 * 4);
    float* d2n  = (float*)alloc((size_t)8 * 49 * 128 * 4);
    float* d3n  = (float*)alloc((size_t)8 * 16 * 128 * 4);
    float* sc   = (float*)alloc((size_t)8 * NA * 4);
    int*  boxes = (int*)alloc((size_t)8 * 6 * 4 * 4);
    size_t avail = (ws_size > off) ? (ws_size - off) : 0;
    float* P = (float*)(ws + off);

    long long s1 = (long long)(avail / ((size_t)1568 * 128 * 4));
    if (s1 > 48) s1 = 48;
    if (s1 < 1)  s1 = 1;
    int S1 = (int)s1;
    int chunk1 = ((K1TOT + S1 * 32 - 1) / (S1 * 32)) * 32;

    // prep (weights + conv1 input)
    k_prep_b<<<dim3(9, 128), 256, 0, stream>>>(wd1, b1h, b1l);
    k_prep_w23<<<dim3(9, 128, 2), 128, 0, stream>>>(wd2, wd3, b2h, b2l, b3h, b3l);
    k_prep_a<<<dim3(32, 4, 8), 256, 0, stream>>>(rpn, ahb, alb);

    // conv1: M=1568, CIN=2048
    k_conv_mfma<196, 14, 1, 2048, 1568><<<dim3(13, S1), 256, 0, stream>>>(
        (const short*)ahb, (const short*)alb, (const short*)b1h, (const short*)b1l, P, chunk1);
    k_reduce_pad<196, 14><<<dim3(1024), 256, 0, stream>>>(P, bd1, d1n, d1ph, d1pl, S1);

    // conv2: M=392, CIN=128, K=1152, split 9x128
    k_conv_mfma<49, 7, 2, 128, 392><<<dim3(4, 9), 256, 0, stream>>>(
        (const short*)d1ph, (const short*)d1pl, (const short*)b2h, (const short*)b2l, P, 128);
    k_reduce_pad<49, 7><<<dim3(1024), 256, 0, stream>>>(P, bd2, d2n, d2ph, d2pl, 9);

    // conv3: M=128, CIN=128, K=1152, split 9x128
    k_conv_mfma<16, 4, 2, 128, 128><<<dim3(1, 9), 256, 0, stream>>>(
        (const short*)d2ph, (const short*)d2pl, (const short*)b3h, (const short*)b3l, P, 128);
    k_reduce3<<<dim3(64), 256, 0, stream>>>(P, bd3, d3n, 9);

    k_heads<<<dim3((8 * NA + 255) / 256), 256, 0, stream>>>(d1n, d2n, d3n,
        hw1, hb1, hw2, hb2, hw3, hb3, sc);
    k_nms_topk<<<dim3(8), 256, 0, stream>>>(sc, anch, out, boxes);
    k_crop<<<dim3(8 * 6 * 3 * 224), 256, 0, stream>>>(x, boxes, out);
}